// Round 1
// baseline (93.708 us; speedup 1.0000x reference)
//
#include <hip/hip_runtime.h>
#include <math.h>

#define D_MODEL 4096
#define D_INNER 8192
#define D_STATE 64
#define PROJ_OUT (2 * D_INNER + 2 * D_STATE + 1)  // 16513

// ---------------------------------------------------------------------------
// Kernel 1: proj = W_in @ x   (PROJ_OUT rows, D_MODEL cols, row-major W)
// One row per wave64. x staged in LDS (16 KB). float4 loads, coalesced:
// lane l reads cols [k + 4l .. k + 4l + 3], wave covers 256 consecutive floats.
// ---------------------------------------------------------------------------
__global__ void __launch_bounds__(256) matvec_in_kernel(
    const float* __restrict__ W, const float* __restrict__ x,
    float* __restrict__ proj) {
    __shared__ float xs[D_MODEL];
    for (int i = threadIdx.x; i < D_MODEL / 4; i += blockDim.x)
        reinterpret_cast<float4*>(xs)[i] = reinterpret_cast<const float4*>(x)[i];
    __syncthreads();

    const int wave = threadIdx.x >> 6;
    const int lane = threadIdx.x & 63;
    const int row  = blockIdx.x * 4 + wave;
    if (row >= PROJ_OUT) return;

    const float* Wr = W + (size_t)row * D_MODEL;
    float acc = 0.f;
    #pragma unroll
    for (int k = lane * 4; k < D_MODEL; k += 64 * 4) {
        float4 w  = *reinterpret_cast<const float4*>(Wr + k);
        float4 xv = *reinterpret_cast<const float4*>(xs + k);
        acc += w.x * xv.x + w.y * xv.y + w.z * xv.z + w.w * xv.w;
    }
    #pragma unroll
    for (int off = 32; off; off >>= 1) acc += __shfl_down(acc, off, 64);
    if (lane == 0) proj[row] = acc;
}

// ---------------------------------------------------------------------------
// Kernel 2: SSM state update + gating.
// One wave per d-row of state. lane = s (coalesced 256B row reads/writes).
//   h[d,s] = state[d,s]*decay[s] + x_ssm[d]*(dt*B[s])
//   y[d]   = sum_s h[d,s]*C[s] + D[d]*x_ssm[d]
//   g[d]   = y[d] * silu(z[d])
// ---------------------------------------------------------------------------
__global__ void __launch_bounds__(256) ssm_kernel(
    const float* __restrict__ proj, const float* __restrict__ state,
    const float* __restrict__ A_log, const float* __restrict__ Dvec,
    float* __restrict__ h_out, float* __restrict__ g) {
    const int wave = threadIdx.x >> 6;
    const int lane = threadIdx.x & 63;  // s index
    const int d    = blockIdx.x * 4 + wave;
    if (d >= D_INNER) return;

    // scalar dt (softplus), per-lane decay/B/C — all tiny, L2-resident
    const float dt_raw = proj[2 * D_INNER + 2 * D_STATE];
    const float dt = (dt_raw > 20.f) ? dt_raw : log1pf(expf(dt_raw));
    const float A  = -expf(A_log[lane]);
    const float decay = expf(A * dt);
    const float B = proj[2 * D_INNER + lane];
    const float C = proj[2 * D_INNER + D_STATE + lane];

    const float xr = proj[D_INNER + d];
    const float x_ssm = xr / (1.f + expf(-xr));  // silu

    const float st = state[(size_t)d * D_STATE + lane];
    const float h  = st * decay + x_ssm * (dt * B);
    h_out[(size_t)d * D_STATE + lane] = h;

    float yv = h * C;
    #pragma unroll
    for (int off = 32; off; off >>= 1) yv += __shfl_down(yv, off, 64);
    if (lane == 0) {
        const float y = yv + Dvec[d] * x_ssm;
        const float z = proj[d];
        const float sz = z / (1.f + expf(-z));  // silu(z)
        g[d] = y * sz;
    }
}

// ---------------------------------------------------------------------------
// Kernel 3: out = W_out @ g   (D_MODEL rows, D_INNER cols)
// Same structure; g staged in LDS (32 KB).
// ---------------------------------------------------------------------------
__global__ void __launch_bounds__(256) matvec_out_kernel(
    const float* __restrict__ W, const float* __restrict__ g,
    float* __restrict__ out) {
    __shared__ float gs[D_INNER];
    for (int i = threadIdx.x; i < D_INNER / 4; i += blockDim.x)
        reinterpret_cast<float4*>(gs)[i] = reinterpret_cast<const float4*>(g)[i];
    __syncthreads();

    const int wave = threadIdx.x >> 6;
    const int lane = threadIdx.x & 63;
    const int row  = blockIdx.x * 4 + wave;
    if (row >= D_MODEL) return;

    const float* Wr = W + (size_t)row * D_INNER;
    float acc = 0.f;
    #pragma unroll
    for (int k = lane * 4; k < D_INNER; k += 64 * 4) {
        float4 w  = *reinterpret_cast<const float4*>(Wr + k);
        float4 xv = *reinterpret_cast<const float4*>(gs + k);
        acc += w.x * xv.x + w.y * xv.y + w.z * xv.z + w.w * xv.w;
    }
    #pragma unroll
    for (int off = 32; off; off >>= 1) acc += __shfl_down(acc, off, 64);
    if (lane == 0) out[row] = acc;
}

extern "C" void kernel_launch(void* const* d_in, const int* in_sizes, int n_in,
                              void* d_out, int out_size, void* d_ws, size_t ws_size,
                              hipStream_t stream) {
    const float* x     = (const float*)d_in[0];
    const float* state = (const float*)d_in[1];
    const float* W_in  = (const float*)d_in[2];
    const float* A_log = (const float*)d_in[3];
    const float* Dvec  = (const float*)d_in[4];
    const float* W_out = (const float*)d_in[5];

    float* out   = (float*)d_out;          // [4096]
    float* h_out = out + D_MODEL;          // [8192*64]

    float* proj = (float*)d_ws;            // [16513]
    float* g    = proj + PROJ_OUT;         // [8192]

    matvec_in_kernel<<<(PROJ_OUT + 3) / 4, 256, 0, stream>>>(W_in, x, proj);
    ssm_kernel<<<D_INNER / 4, 256, 0, stream>>>(proj, state, A_log, Dvec, h_out, g);
    matvec_out_kernel<<<D_MODEL / 4, 256, 0, stream>>>(W_out, g, out);
}

// Round 2
// 91.409 us; speedup vs baseline: 1.0251x; 1.0251x over previous
//
#include <hip/hip_runtime.h>
#include <math.h>

#define D_MODEL 4096
#define D_INNER 8192
#define D_STATE 64
#define PROJ_OUT (2 * D_INNER + 2 * D_STATE + 1)  // 16513

// ---------------------------------------------------------------------------
// Kernel 1: proj = W_in @ x   (PROJ_OUT rows x D_MODEL cols, row-major W)
// 8 rows/block, 2 rows/wave. x staged once in LDS, shared by both rows.
// Per k-iteration: 1 ds_read_b128 + 2 global float4 loads + 8 FMA.
// ---------------------------------------------------------------------------
__global__ void __launch_bounds__(256) matvec_in_kernel(
    const float* __restrict__ W, const float* __restrict__ x,
    float* __restrict__ proj) {
    __shared__ float xs[D_MODEL];
    for (int i = threadIdx.x; i < D_MODEL / 4; i += blockDim.x)
        reinterpret_cast<float4*>(xs)[i] = reinterpret_cast<const float4*>(x)[i];
    __syncthreads();

    const int wave = threadIdx.x >> 6;
    const int lane = threadIdx.x & 63;
    const int row0 = blockIdx.x * 8 + wave * 2;
    if (row0 >= PROJ_OUT) return;
    const int row1 = row0 + 1;
    const bool has1 = (row1 < PROJ_OUT);

    const float* Wr0 = W + (size_t)row0 * D_MODEL;
    const float* Wr1 = has1 ? (Wr0 + D_MODEL) : Wr0;  // safe dup if masked

    float acc0 = 0.f, acc1 = 0.f;
    #pragma unroll
    for (int k = lane * 4; k < D_MODEL; k += 64 * 4) {
        float4 xv = *reinterpret_cast<const float4*>(xs + k);
        float4 w0 = *reinterpret_cast<const float4*>(Wr0 + k);
        float4 w1 = *reinterpret_cast<const float4*>(Wr1 + k);
        acc0 += w0.x * xv.x + w0.y * xv.y + w0.z * xv.z + w0.w * xv.w;
        acc1 += w1.x * xv.x + w1.y * xv.y + w1.z * xv.z + w1.w * xv.w;
    }
    #pragma unroll
    for (int off = 32; off; off >>= 1) {
        acc0 += __shfl_down(acc0, off, 64);
        acc1 += __shfl_down(acc1, off, 64);
    }
    if (lane == 0) {
        proj[row0] = acc0;
        if (has1) proj[row1] = acc1;
    }
}

// ---------------------------------------------------------------------------
// Kernel 2: SSM state update + gating. float4-vectorized over states.
// Wave handles 4 d-rows: lane = group(2b: which d) * 16 + sl(4b);
// each lane owns states [4*sl, 4*sl+4).  1 KB contiguous per wave instr.
// ---------------------------------------------------------------------------
__global__ void __launch_bounds__(256) ssm_kernel(
    const float* __restrict__ proj, const float* __restrict__ state,
    const float* __restrict__ A_log, const float* __restrict__ Dvec,
    float* __restrict__ h_out, float* __restrict__ g) {
    const int wave  = threadIdx.x >> 6;
    const int lane  = threadIdx.x & 63;
    const int group = lane >> 4;      // which of 4 d-rows in this wave
    const int sl    = lane & 15;      // state sub-lane: owns s = 4*sl..4*sl+3
    const int d     = blockIdx.x * 16 + wave * 4 + group;

    const float dt_raw = proj[2 * D_INNER + 2 * D_STATE];
    const float dt = (dt_raw > 20.f) ? dt_raw : log1pf(expf(dt_raw));

    const float4 Al = *reinterpret_cast<const float4*>(A_log + 4 * sl);
    const float4 Bv = *reinterpret_cast<const float4*>(proj + 2 * D_INNER + 4 * sl);
    const float4 Cv = *reinterpret_cast<const float4*>(proj + 2 * D_INNER + D_STATE + 4 * sl);

    const float xr = proj[D_INNER + d];
    const float x_ssm = xr / (1.f + expf(-xr));

    const float4 st = *reinterpret_cast<const float4*>(state + (size_t)d * D_STATE + 4 * sl);
    float4 h;
    h.x = st.x * expf(-expf(Al.x) * dt) + x_ssm * (dt * Bv.x);
    h.y = st.y * expf(-expf(Al.y) * dt) + x_ssm * (dt * Bv.y);
    h.z = st.z * expf(-expf(Al.z) * dt) + x_ssm * (dt * Bv.z);
    h.w = st.w * expf(-expf(Al.w) * dt) + x_ssm * (dt * Bv.w);
    *reinterpret_cast<float4*>(h_out + (size_t)d * D_STATE + 4 * sl) = h;

    float yv = h.x * Cv.x + h.y * Cv.y + h.z * Cv.z + h.w * Cv.w;
    #pragma unroll
    for (int off = 8; off; off >>= 1) yv += __shfl_xor(yv, off, 64);  // 16-lane group reduce
    if (sl == 0) {
        const float y = yv + Dvec[d] * x_ssm;
        const float z = proj[d];
        g[d] = y * (z / (1.f + expf(-z)));
    }
}

// ---------------------------------------------------------------------------
// Kernel 3: out = W_out @ g   (D_MODEL rows x D_INNER cols)
// Same 2-rows-per-wave structure; g staged in LDS (32 KB).
// ---------------------------------------------------------------------------
__global__ void __launch_bounds__(256) matvec_out_kernel(
    const float* __restrict__ W, const float* __restrict__ g,
    float* __restrict__ out) {
    __shared__ float gs[D_INNER];
    for (int i = threadIdx.x; i < D_INNER / 4; i += blockDim.x)
        reinterpret_cast<float4*>(gs)[i] = reinterpret_cast<const float4*>(g)[i];
    __syncthreads();

    const int wave = threadIdx.x >> 6;
    const int lane = threadIdx.x & 63;
    const int row0 = blockIdx.x * 8 + wave * 2;
    const int row1 = row0 + 1;

    const float* Wr0 = W + (size_t)row0 * D_INNER;
    const float* Wr1 = Wr0 + D_INNER;

    float acc0 = 0.f, acc1 = 0.f;
    #pragma unroll 8
    for (int k = lane * 4; k < D_INNER; k += 64 * 4) {
        float4 xv = *reinterpret_cast<const float4*>(gs + k);
        float4 w0 = *reinterpret_cast<const float4*>(Wr0 + k);
        float4 w1 = *reinterpret_cast<const float4*>(Wr1 + k);
        acc0 += w0.x * xv.x + w0.y * xv.y + w0.z * xv.z + w0.w * xv.w;
        acc1 += w1.x * xv.x + w1.y * xv.y + w1.z * xv.z + w1.w * xv.w;
    }
    #pragma unroll
    for (int off = 32; off; off >>= 1) {
        acc0 += __shfl_down(acc0, off, 64);
        acc1 += __shfl_down(acc1, off, 64);
    }
    if (lane == 0) {
        out[row0] = acc0;
        out[row1] = acc1;
    }
}

extern "C" void kernel_launch(void* const* d_in, const int* in_sizes, int n_in,
                              void* d_out, int out_size, void* d_ws, size_t ws_size,
                              hipStream_t stream) {
    const float* x     = (const float*)d_in[0];
    const float* state = (const float*)d_in[1];
    const float* W_in  = (const float*)d_in[2];
    const float* A_log = (const float*)d_in[3];
    const float* Dvec  = (const float*)d_in[4];
    const float* W_out = (const float*)d_in[5];

    float* out   = (float*)d_out;          // [4096]
    float* h_out = out + D_MODEL;          // [8192*64]

    float* proj = (float*)d_ws;            // [16513]
    float* g    = proj + PROJ_OUT;         // [8192]

    matvec_in_kernel<<<(PROJ_OUT + 7) / 8, 256, 0, stream>>>(W_in, x, proj);
    ssm_kernel<<<D_INNER / 16, 256, 0, stream>>>(proj, state, A_log, Dvec, h_out, g);
    matvec_out_kernel<<<D_MODEL / 8, 256, 0, stream>>>(W_out, g, out);
}

// Round 3
// 71.434 us; speedup vs baseline: 1.3118x; 1.2796x over previous
//
#include <hip/hip_runtime.h>
#include <math.h>

#define D_MODEL 4096
#define D_INNER 8192
#define D_STATE 64
#define PROJ_OUT (2 * D_INNER + 2 * D_STATE + 1)  // 16513

typedef float f32x4 __attribute__((ext_vector_type(4)));

// ws layout (floats):
#define NSEG1 4
#define PP1_STRIDE 16516                 // PROJ_OUT padded to x4
#define G_OFF (NSEG1 * PP1_STRIDE)       // 66064
#define NSEG3 8
#define OP_OFF (G_OFF + D_INNER)         // 74256, out_part: 8 x 4096

// ---------------------------------------------------------------------------
// Kernel 1: partial proj. Unit = (row-pair, 1/4 of columns) per wave.
// Block = 4 waves, same column segment, 4 consecutive row-pairs.
// No LDS, no syncthreads: x read directly (L2-resident, 16 KB).
// W_in loads nontemporal (single-use, > L3; keep L3 clean for W_out).
// ---------------------------------------------------------------------------
__global__ void __launch_bounds__(256) matvec_in_kernel(
    const float* __restrict__ W, const float* __restrict__ x,
    float* __restrict__ pp) {
    const int wave = threadIdx.x >> 6;
    const int lane = threadIdx.x & 63;
    const int seg  = blockIdx.x & (NSEG1 - 1);
    const int pair = (blockIdx.x >> 2) * 4 + wave;
    const int row0 = pair * 2;
    if (row0 >= PROJ_OUT) return;
    const int row1 = row0 + 1;
    const bool has1 = (row1 < PROJ_OUT);

    const int k0 = seg * (D_MODEL / NSEG1);  // 1024-col segment
    const float* Wr0 = W + (size_t)row0 * D_MODEL + k0;
    const float* Wr1 = has1 ? (Wr0 + D_MODEL) : Wr0;
    const float* xp  = x + k0;

    float acc0 = 0.f, acc1 = 0.f;
    #pragma unroll
    for (int k = lane * 4; k < D_MODEL / NSEG1; k += 64 * 4) {
        f32x4 xv = *reinterpret_cast<const f32x4*>(xp + k);
        f32x4 w0 = __builtin_nontemporal_load(reinterpret_cast<const f32x4*>(Wr0 + k));
        f32x4 w1 = __builtin_nontemporal_load(reinterpret_cast<const f32x4*>(Wr1 + k));
        acc0 += w0.x * xv.x + w0.y * xv.y + w0.z * xv.z + w0.w * xv.w;
        acc1 += w1.x * xv.x + w1.y * xv.y + w1.z * xv.z + w1.w * xv.w;
    }
    #pragma unroll
    for (int off = 32; off; off >>= 1) {
        acc0 += __shfl_down(acc0, off, 64);
        acc1 += __shfl_down(acc1, off, 64);
    }
    if (lane == 0) {
        pp[seg * PP1_STRIDE + row0] = acc0;
        if (has1) pp[seg * PP1_STRIDE + row1] = acc1;
    }
}

// ---------------------------------------------------------------------------
// Kernel 2: SSM update + gating; sums the 4 column-partials inline.
// Wave handles 4 d-rows: lane = group(2b)*16 + sl(4b); lane owns 4 states.
// ---------------------------------------------------------------------------
__global__ void __launch_bounds__(256) ssm_kernel(
    const float* __restrict__ pp, const float* __restrict__ state,
    const float* __restrict__ A_log, const float* __restrict__ Dvec,
    float* __restrict__ h_out, float* __restrict__ g) {
    const int wave  = threadIdx.x >> 6;
    const int lane  = threadIdx.x & 63;
    const int group = lane >> 4;
    const int sl    = lane & 15;
    const int d     = blockIdx.x * 16 + wave * 4 + group;

    float dt_raw = 0.f, z = 0.f, xr = 0.f;
    f32x4 Bv = {0.f, 0.f, 0.f, 0.f}, Cv = {0.f, 0.f, 0.f, 0.f};
    #pragma unroll
    for (int p = 0; p < NSEG1; ++p) {
        const float* b = pp + p * PP1_STRIDE;
        dt_raw += b[2 * D_INNER + 2 * D_STATE];
        z      += b[d];
        xr     += b[D_INNER + d];
        f32x4 bb = *reinterpret_cast<const f32x4*>(b + 2 * D_INNER + 4 * sl);
        f32x4 cc = *reinterpret_cast<const f32x4*>(b + 2 * D_INNER + D_STATE + 4 * sl);
        Bv += bb; Cv += cc;
    }
    const float dt = (dt_raw > 20.f) ? dt_raw : log1pf(expf(dt_raw));
    const f32x4 Al = *reinterpret_cast<const f32x4*>(A_log + 4 * sl);
    const float x_ssm = xr / (1.f + expf(-xr));

    const f32x4 st = *reinterpret_cast<const f32x4*>(state + (size_t)d * D_STATE + 4 * sl);
    f32x4 h;
    h.x = st.x * expf(-expf(Al.x) * dt) + x_ssm * (dt * Bv.x);
    h.y = st.y * expf(-expf(Al.y) * dt) + x_ssm * (dt * Bv.y);
    h.z = st.z * expf(-expf(Al.z) * dt) + x_ssm * (dt * Bv.z);
    h.w = st.w * expf(-expf(Al.w) * dt) + x_ssm * (dt * Bv.w);
    *reinterpret_cast<f32x4*>(h_out + (size_t)d * D_STATE + 4 * sl) = h;

    float yv = h.x * Cv.x + h.y * Cv.y + h.z * Cv.z + h.w * Cv.w;
    #pragma unroll
    for (int off = 8; off; off >>= 1) yv += __shfl_xor(yv, off, 64);
    if (sl == 0) {
        const float y = yv + Dvec[d] * x_ssm;
        g[d] = y * (z / (1.f + expf(-z)));
    }
}

// ---------------------------------------------------------------------------
// Kernel 3: partial out. Unit = (row-pair, 1/8 of columns) per wave.
// g read directly from L2 (32 KB). W_out cached (L3-resident across replays).
// ---------------------------------------------------------------------------
__global__ void __launch_bounds__(256) matvec_out_kernel(
    const float* __restrict__ W, const float* __restrict__ g,
    float* __restrict__ op) {
    const int wave = threadIdx.x >> 6;
    const int lane = threadIdx.x & 63;
    const int seg  = blockIdx.x & (NSEG3 - 1);
    const int pair = (blockIdx.x >> 3) * 4 + wave;
    const int row0 = pair * 2;
    if (row0 >= D_MODEL) return;
    const int row1 = row0 + 1;

    const int k0 = seg * (D_INNER / NSEG3);  // 1024-col segment
    const float* Wr0 = W + (size_t)row0 * D_INNER + k0;
    const float* Wr1 = Wr0 + D_INNER;
    const float* gp  = g + k0;

    float acc0 = 0.f, acc1 = 0.f;
    #pragma unroll
    for (int k = lane * 4; k < D_INNER / NSEG3; k += 64 * 4) {
        f32x4 xv = *reinterpret_cast<const f32x4*>(gp + k);
        f32x4 w0 = *reinterpret_cast<const f32x4*>(Wr0 + k);
        f32x4 w1 = *reinterpret_cast<const f32x4*>(Wr1 + k);
        acc0 += w0.x * xv.x + w0.y * xv.y + w0.z * xv.z + w0.w * xv.w;
        acc1 += w1.x * xv.x + w1.y * xv.y + w1.z * xv.z + w1.w * xv.w;
    }
    #pragma unroll
    for (int off = 32; off; off >>= 1) {
        acc0 += __shfl_down(acc0, off, 64);
        acc1 += __shfl_down(acc1, off, 64);
    }
    if (lane == 0) {
        op[seg * D_MODEL + row0] = acc0;
        op[seg * D_MODEL + row1] = acc1;
    }
}

// ---------------------------------------------------------------------------
// Kernel 4: fold the 8 column-partials of out. 4096 threads.
// ---------------------------------------------------------------------------
__global__ void __launch_bounds__(256) fold_out_kernel(
    const float* __restrict__ op, float* __restrict__ out) {
    const int i = blockIdx.x * 256 + threadIdx.x;
    float s = 0.f;
    #pragma unroll
    for (int p = 0; p < NSEG3; ++p) s += op[p * D_MODEL + i];
    out[i] = s;
}

extern "C" void kernel_launch(void* const* d_in, const int* in_sizes, int n_in,
                              void* d_out, int out_size, void* d_ws, size_t ws_size,
                              hipStream_t stream) {
    const float* x     = (const float*)d_in[0];
    const float* state = (const float*)d_in[1];
    const float* W_in  = (const float*)d_in[2];
    const float* A_log = (const float*)d_in[3];
    const float* Dvec  = (const float*)d_in[4];
    const float* W_out = (const float*)d_in[5];

    float* out   = (float*)d_out;          // [4096]
    float* h_out = out + D_MODEL;          // [8192*64]

    float* pp = (float*)d_ws;              // [4][16516] proj partials
    float* g  = pp + G_OFF;                // [8192]
    float* op = pp + OP_OFF;               // [8][4096] out partials

    // k1: pairs = 8257 -> (8260/4)=2065 pair-groups x 4 segs = 8260 blocks
    matvec_in_kernel<<<2065 * NSEG1, 256, 0, stream>>>(W_in, x, pp);
    ssm_kernel<<<D_INNER / 16, 256, 0, stream>>>(pp, state, A_log, Dvec, h_out, g);
    // k3: pairs = 2048 -> 512 pair-groups x 8 segs = 4096 blocks
    matvec_out_kernel<<<512 * NSEG3, 256, 0, stream>>>(W_out, g, op);
    fold_out_kernel<<<D_MODEL / 256, 256, 0, stream>>>(op, out);
}